// Round 3
// baseline (962.256 us; speedup 1.0000x reference)
//
#include <hip/hip_runtime.h>
#include <stdint.h>

#define NB 16
#define CC 32
#define HH 224
#define WW 224
#define HWP (HH*WW)          // 50176
#define NHWP (NB*HWP)        // 802816
#define PW 226
#define PSZ (PW*PW)          // 51076 padded words per image

// workspace layout (bytes)
#define OFF_S1   0u
#define OFF_S2   3268864u    // 16*51076*4
#define OFF_WP1  6537728u
#define OFF_WP2  6538880u
#define OFF_SQ1  6540032u    // 32 x u64
#define OFF_SQ2  6540288u    // 32 x u64
#define OFF_SUM1 6540544u    // 32 x i32
#define OFF_SUM2 6540672u    // 32 x i32

// ============ setup: pack weights, zero stats, zero pad borders of s1/s2 ============
__global__ void __launch_bounds__(256) k_setup(const uint32_t* __restrict__ w1,
                                               const uint32_t* __restrict__ w2,
                                               char* __restrict__ ws) {
    int t = blockIdx.x * 256 + threadIdx.x;
    if (t < 576) {
        const uint32_t* w = (t < 288) ? w1 : w2;
        uint32_t* o = (uint32_t*)(ws + ((t < 288) ? OFF_WP1 : OFF_WP2));
        int idx = (t < 288) ? t : t - 288;
        int oc = idx / 9, k = idx - oc * 9;
        uint32_t word = 0;
        for (int i = 0; i < 32; ++i)
            word |= (w[(oc * 32 + i) * 9 + k] >> 31) << i;
        o[idx] = word;
    } else if (t < 768) {
        ((uint32_t*)(ws + OFF_SQ1))[t - 576] = 0u;   // 192 words: sq1,sq2,sum1,sum2
    } else if (t >= 1024 && t < 1024 + 28800) {
        int b = t - 1024;
        uint32_t* buf = (uint32_t*)(ws + ((b < 14400) ? OFF_S1 : OFF_S2));
        int bb = (b < 14400) ? b : b - 14400;
        int n = bb / 900;
        int e = bb - n * 900;
        int row, col;
        if (e < 226)      { row = 0;   col = e; }
        else if (e < 452) { row = 225; col = e - 226; }
        else { int k = e - 452; row = 1 + (k >> 1); col = (k & 1) ? 225 : 0; }
        buf[(size_t)n * PSZ + row * PW + col] = 0u;
    }
}

// ============ pack activation signs into padded layout ============
__global__ void __launch_bounds__(256) k_packx(const uint32_t* __restrict__ x,
                                               uint32_t* __restrict__ sp) {
    int t = blockIdx.x * 256 + threadIdx.x;        // 16 * 12544 threads, 4 px each
    int n = t / (HWP / 4);
    int rem4 = t - n * (HWP / 4);
    int px0 = rem4 * 4;
    int r = px0 / WW;
    int cw0 = px0 - r * WW;                        // row-aligned: 224 % 4 == 0
    const uint32_t* xp = x + (size_t)n * CC * HWP + px0;
    uint32_t w0 = 0, w1 = 0, w2 = 0, w3 = 0;
    #pragma unroll
    for (int c = 0; c < 32; ++c) {
        uint4 v = *reinterpret_cast<const uint4*>(xp + (size_t)c * HWP);
        w0 |= (v.x >> 31) << c;
        w1 |= (v.y >> 31) << c;
        w2 |= (v.z >> 31) << c;
        w3 |= (v.w >> 31) << c;
    }
    uint32_t* op = sp + (size_t)n * PSZ + (r + 1) * PW + (cw0 + 1);
    op[0] = w0; op[1] = w1; op[2] = w2; op[3] = w3;
}

// ============ LDS staging: weights [32][12] (16B rows) + border table ============
// Ctab[ty][oc] = sum over pad taps of (32 - 2*popc(w)); ty bits: 1=top,2=bot,4=left,8=right
__device__ __forceinline__ void stage_lds(const uint32_t* __restrict__ wp,
                                          uint32_t (*Wl)[12], int (*Ctab)[32]) {
    for (int i = threadIdx.x; i < 288; i += 256) {
        int oc = i / 9, k = i - oc * 9;
        Wl[oc][k] = wp[i];
    }
    for (int i = threadIdx.x; i < 512; i += 256) {
        int ty = i >> 5, oc = i & 31;
        int s = 0;
        #pragma unroll
        for (int t = 0; t < 9; ++t) {
            int dh = t / 3 - 1, dw = t % 3 - 1;
            bool pad = ((ty & 1) && dh < 0) || ((ty & 2) && dh > 0) ||
                       ((ty & 4) && dw < 0) || ((ty & 8) && dw > 0);
            if (pad) s += 32 - 2 * __popc(wp[oc * 9 + t]);
        }
        Ctab[ty][oc] = s;
    }
}

// ============ common: thread -> (n, row, col-group) ============
__device__ __forceinline__ void decode_grp(int t, int& n, int& r, int& cw0) {
    n = t / 12544;                 // 56 groups * 224 rows per image
    int rem = t - n * 12544;
    r = rem / 56;
    cw0 = (rem - r * 56) * 4;
}

// 18 tap words for 4 consecutive pixels (row-aligned), padded layout
#define LOAD_TAPS18(base)                                                        \
    uint32_t u0 = (base)[-PW-1], u1 = (base)[-PW],   u2 = (base)[-PW+1],         \
             u3 = (base)[-PW+2], u4 = (base)[-PW+3], u5 = (base)[-PW+4];         \
    uint32_t m0 = (base)[-1],    m1 = (base)[0],     m2 = (base)[1],             \
             m3 = (base)[2],     m4 = (base)[3],     m5 = (base)[4];             \
    uint32_t l0 = (base)[PW-1],  l1 = (base)[PW],    l2 = (base)[PW+1],          \
             l3 = (base)[PW+2],  l4 = (base)[PW+3],  l5 = (base)[PW+4];

// Per-oc conv of 4 px, weights + border corr from LDS.
// sched_barrier(0) pins the LDS reads to their iteration -> no 288-load hoist/spill.
#define CONV4L(oc_)                                                              \
    __builtin_amdgcn_sched_barrier(0);                                           \
    const uint32_t* wr = &Wl[oc_][0];                                            \
    uint32_t w0 = wr[0], w1 = wr[1], w2 = wr[2], w3 = wr[3], w4 = wr[4],         \
             w5 = wr[5], w6 = wr[6], w7 = wr[7], w8 = wr[8];                     \
    int pc0 = __popc(u0^w0)+__popc(u1^w1)+__popc(u2^w2)                          \
            + __popc(m0^w3)+__popc(m1^w4)+__popc(m2^w5)                          \
            + __popc(l0^w6)+__popc(l1^w7)+__popc(l2^w8);                         \
    int pc1 = __popc(u1^w0)+__popc(u2^w1)+__popc(u3^w2)                          \
            + __popc(m1^w3)+__popc(m2^w4)+__popc(m3^w5)                          \
            + __popc(l1^w6)+__popc(l2^w7)+__popc(l3^w8);                         \
    int pc2 = __popc(u2^w0)+__popc(u3^w1)+__popc(u4^w2)                          \
            + __popc(m2^w3)+__popc(m3^w4)+__popc(m4^w5)                          \
            + __popc(l2^w6)+__popc(l3^w7)+__popc(l4^w8);                         \
    int pc3 = __popc(u3^w0)+__popc(u4^w1)+__popc(u5^w2)                          \
            + __popc(m3^w3)+__popc(m4^w4)+__popc(m5^w5)                          \
            + __popc(l3^w6)+__popc(l4^w7)+__popc(l5^w8);                         \
    int c0 = 288 - 2*pc0 - Ctab[ty0][oc_];                                       \
    int c1 = 288 - 2*pc1 - Ctab[rb][oc_];                                        \
    int c2 = 288 - 2*pc2 - Ctab[rb][oc_];                                        \
    int c3 = 288 - 2*pc3 - Ctab[ty3][oc_];

#define DECODE_BORDER()                                                          \
    int rb = (r == 0) ? 1 : (r == HH - 1) ? 2 : 0;                               \
    int ty0 = rb | ((cw0 == 0) ? 4 : 0);                                         \
    int ty3 = rb | ((cw0 == WW - 4) ? 8 : 0);

// merge-tree wave reduction: 32 per-lane values -> per-oc wave sums.
// after: lane L in [0,32) holds total for oc = bitrev5(L)
__device__ __forceinline__ void wave_reduce32(int (&v)[32]) {
    int lane = threadIdx.x & 63;
    #pragma unroll
    for (int s = 0; s < 5; ++s) {
        const int d = 1 << s, half = 16 >> s;
        bool hi = (lane & d) != 0;
        #pragma unroll
        for (int i = 0; i < half; ++i) {
            int sent = hi ? v[i] : v[i + half];
            int recv = __shfl_xor(sent, d, 64);
            v[i] = (hi ? v[i + half] : v[i]) + recv;
        }
    }
    v[0] += __shfl_xor(v[0], 32, 64);
}

// ============ conv + exact per-channel sum / sumsq ============
__global__ void __launch_bounds__(256) k_stats(const uint32_t* __restrict__ sp,
                                               const uint32_t* __restrict__ wp,
                                               int* __restrict__ g_sum,
                                               unsigned long long* __restrict__ g_sq) {
    __shared__ __align__(16) uint32_t Wl[32][12];
    __shared__ int Ctab[16][32];
    stage_lds(wp, Wl, Ctab);
    __syncthreads();

    int t = blockIdx.x * 256 + threadIdx.x;        // 784 blocks, 4 px/thread
    int n, r, cw0; decode_grp(t, n, r, cw0);
    const uint32_t* base = sp + (size_t)n * PSZ + (r + 1) * PW + (cw0 + 1);
    LOAD_TAPS18(base)
    DECODE_BORDER()

    int acc_s[32], acc_q[32];
    #pragma unroll
    for (int oc = 0; oc < 32; ++oc) {
        CONV4L(oc)
        acc_s[oc] = c0 + c1 + c2 + c3;
        acc_q[oc] = c0*c0 + c1*c1 + c2*c2 + c3*c3;
    }

    wave_reduce32(acc_s);
    wave_reduce32(acc_q);

    __shared__ int ls[4][32], lq[4][32];
    int lane = threadIdx.x & 63, wid = threadIdx.x >> 6;
    if (lane < 32) {
        int oc = __brev((uint32_t)lane) >> 27;     // bitrev5
        ls[wid][oc] = acc_s[0];
        lq[wid][oc] = acc_q[0];
    }
    __syncthreads();
    if (threadIdx.x < 32) {
        int s = ls[0][threadIdx.x] + ls[1][threadIdx.x] + ls[2][threadIdx.x] + ls[3][threadIdx.x];
        int q = lq[0][threadIdx.x] + lq[1][threadIdx.x] + lq[2][threadIdx.x] + lq[3][threadIdx.x];
        atomicAdd(&g_sum[threadIdx.x], s);
        atomicAdd(&g_sq[threadIdx.x], (unsigned long long)(long long)q);
    }
}

// ============ per-block BN affine from exact int stats ============
__device__ __forceinline__ void build_affine(const int* __restrict__ g_sum,
                                             const unsigned long long* __restrict__ g_sq,
                                             const float* __restrict__ gamma,
                                             const float* __restrict__ beta,
                                             float* aL, float* dL) {
    if (threadIdx.x < 32) {
        int c = threadIdx.x;
        double M = (double)NHWP;
        double mean = (double)g_sum[c] / M;
        double ex2 = (double)(long long)g_sq[c] / M;
        double var = ex2 - mean * mean;
        double inv = 1.0 / sqrt(var + 1e-5);
        double aa = inv * (double)gamma[c];
        aL[c] = (float)aa;
        dL[c] = (float)((double)beta[c] - aa * mean);
    }
}

// ============ conv1 + BN1 + sign -> packed padded s2 ============
__global__ void __launch_bounds__(256) k_sign(const uint32_t* __restrict__ sp,
                                              const uint32_t* __restrict__ wp,
                                              const int* __restrict__ g_sum,
                                              const unsigned long long* __restrict__ g_sq,
                                              const float* __restrict__ gamma,
                                              const float* __restrict__ beta,
                                              uint32_t* __restrict__ op) {
    __shared__ __align__(16) uint32_t Wl[32][12];
    __shared__ int Ctab[16][32];
    __shared__ float aL[32], dL[32];
    stage_lds(wp, Wl, Ctab);
    build_affine(g_sum, g_sq, gamma, beta, aL, dL);
    __syncthreads();

    int t = blockIdx.x * 256 + threadIdx.x;        // 784 blocks, 4 px/thread
    int n, r, cw0; decode_grp(t, n, r, cw0);
    const uint32_t* base = sp + (size_t)n * PSZ + (r + 1) * PW + (cw0 + 1);
    LOAD_TAPS18(base)
    DECODE_BORDER()

    uint32_t wd0 = 0, wd1 = 0, wd2 = 0, wd3 = 0;
    #pragma unroll
    for (int oc = 0; oc < 32; ++oc) {
        CONV4L(oc)
        float a = aL[oc], d = dL[oc];
        // fma never produces -0 unless result is exactly 0 -> sign bit == (y < 0)
        wd0 |= (__float_as_uint(fmaf(a, (float)c0, d)) >> 31) << oc;
        wd1 |= (__float_as_uint(fmaf(a, (float)c1, d)) >> 31) << oc;
        wd2 |= (__float_as_uint(fmaf(a, (float)c2, d)) >> 31) << oc;
        wd3 |= (__float_as_uint(fmaf(a, (float)c3, d)) >> 31) << oc;
    }
    uint32_t* o = op + (size_t)n * PSZ + (r + 1) * PW + (cw0 + 1);
    o[0] = wd0; o[1] = wd1; o[2] = wd2; o[3] = wd3;
}

// ============ conv2 + BN2 + residual -> f32 out (float4 IO) ============
__global__ void __launch_bounds__(256) k_res(const uint32_t* __restrict__ sp,
                                             const uint32_t* __restrict__ wp,
                                             const int* __restrict__ g_sum,
                                             const unsigned long long* __restrict__ g_sq,
                                             const float* __restrict__ gamma,
                                             const float* __restrict__ beta,
                                             const float* __restrict__ x,
                                             float* __restrict__ out) {
    __shared__ __align__(16) uint32_t Wl[32][12];
    __shared__ int Ctab[16][32];
    __shared__ float aL[32], dL[32];
    stage_lds(wp, Wl, Ctab);
    build_affine(g_sum, g_sq, gamma, beta, aL, dL);
    __syncthreads();

    int t = blockIdx.x * 256 + threadIdx.x;        // 784 blocks, 4 px/thread
    int n, r, cw0; decode_grp(t, n, r, cw0);
    const uint32_t* base = sp + (size_t)n * PSZ + (r + 1) * PW + (cw0 + 1);
    LOAD_TAPS18(base)
    DECODE_BORDER()

    size_t pix = (size_t)n * CC * HWP + (size_t)r * WW + cw0;   // 16B aligned
    #pragma unroll
    for (int oc = 0; oc < 32; ++oc) {
        CONV4L(oc)
        float a = aL[oc], d = dL[oc];
        float4 xv = *reinterpret_cast<const float4*>(x + pix + (size_t)oc * HWP);
        float4 ov;
        ov.x = xv.x + fmaf(a, (float)c0, d);
        ov.y = xv.y + fmaf(a, (float)c1, d);
        ov.z = xv.z + fmaf(a, (float)c2, d);
        ov.w = xv.w + fmaf(a, (float)c3, d);
        *reinterpret_cast<float4*>(out + pix + (size_t)oc * HWP) = ov;
    }
}

extern "C" void kernel_launch(void* const* d_in, const int* in_sizes, int n_in,
                              void* d_out, int out_size, void* d_ws, size_t ws_size,
                              hipStream_t stream) {
    const float* x  = (const float*)d_in[0];
    const float* w1 = (const float*)d_in[1];
    const float* g1 = (const float*)d_in[2];
    const float* b1 = (const float*)d_in[3];
    const float* w2 = (const float*)d_in[4];
    const float* g2 = (const float*)d_in[5];
    const float* b2 = (const float*)d_in[6];
    float* out = (float*)d_out;

    char* ws = (char*)d_ws;
    uint32_t* s1  = (uint32_t*)(ws + OFF_S1);
    uint32_t* s2  = (uint32_t*)(ws + OFF_S2);
    uint32_t* wp1 = (uint32_t*)(ws + OFF_WP1);
    uint32_t* wp2 = (uint32_t*)(ws + OFF_WP2);
    unsigned long long* sq1 = (unsigned long long*)(ws + OFF_SQ1);
    unsigned long long* sq2 = (unsigned long long*)(ws + OFF_SQ2);
    int* sum1 = (int*)(ws + OFF_SUM1);
    int* sum2 = (int*)(ws + OFF_SUM2);

    k_setup<<<120, 256, 0, stream>>>((const uint32_t*)w1, (const uint32_t*)w2, ws);
    k_packx<<<784, 256, 0, stream>>>((const uint32_t*)x, s1);
    k_stats<<<784, 256, 0, stream>>>(s1, wp1, sum1, sq1);
    k_sign <<<784, 256, 0, stream>>>(s1, wp1, sum1, sq1, g1, b1, s2);
    k_stats<<<784, 256, 0, stream>>>(s2, wp2, sum2, sq2);
    k_res  <<<784, 256, 0, stream>>>(s2, wp2, sum2, sq2, g2, b2, x, out);
}

// Round 4
// 315.478 us; speedup vs baseline: 3.0502x; 3.0502x over previous
//
#include <hip/hip_runtime.h>
#include <stdint.h>

#define NB 16
#define CC 32
#define HH 224
#define WW 224
#define HWP (HH*WW)          // 50176
#define NHWP (NB*HWP)        // 802816
#define PW 226
#define PSZ (PW*PW)          // 51076 padded words per image

// workspace layout (bytes)
#define OFF_S1   0u
#define OFF_S2   3268864u    // 16*51076*4
#define OFF_WP1  6537728u
#define OFF_WP2  6538880u
#define OFF_SQ1  6540032u    // 32 x u64
#define OFF_SQ2  6540288u    // 32 x u64
#define OFF_SUM1 6540544u    // 32 x i32
#define OFF_SUM2 6540672u    // 32 x i32

// ============ setup: pack weights, zero stats, zero pad borders of s1/s2 ============
__global__ void __launch_bounds__(256) k_setup(const uint32_t* __restrict__ w1,
                                               const uint32_t* __restrict__ w2,
                                               char* __restrict__ ws) {
    int t = blockIdx.x * 256 + threadIdx.x;
    if (t < 576) {
        const uint32_t* w = (t < 288) ? w1 : w2;
        uint32_t* o = (uint32_t*)(ws + ((t < 288) ? OFF_WP1 : OFF_WP2));
        int idx = (t < 288) ? t : t - 288;
        int oc = idx / 9, k = idx - oc * 9;
        uint32_t word = 0;
        for (int i = 0; i < 32; ++i)
            word |= (w[(oc * 32 + i) * 9 + k] >> 31) << i;
        o[idx] = word;
    } else if (t < 768) {
        ((uint32_t*)(ws + OFF_SQ1))[t - 576] = 0u;   // 192 words: sq1,sq2,sum1,sum2
    } else if (t >= 1024 && t < 1024 + 28800) {
        int b = t - 1024;
        uint32_t* buf = (uint32_t*)(ws + ((b < 14400) ? OFF_S1 : OFF_S2));
        int bb = (b < 14400) ? b : b - 14400;
        int n = bb / 900;
        int e = bb - n * 900;
        int row, col;
        if (e < 226)      { row = 0;   col = e; }
        else if (e < 452) { row = 225; col = e - 226; }
        else { int k = e - 452; row = 1 + (k >> 1); col = (k & 1) ? 225 : 0; }
        buf[(size_t)n * PSZ + row * PW + col] = 0u;
    }
}

// ============ pack activation signs into padded layout ============
__global__ void __launch_bounds__(256) k_packx(const uint32_t* __restrict__ x,
                                               uint32_t* __restrict__ sp) {
    int t = blockIdx.x * 256 + threadIdx.x;        // 16 * 12544 threads, 4 px each
    int n = t / (HWP / 4);
    int rem4 = t - n * (HWP / 4);
    int px0 = rem4 * 4;
    int r = px0 / WW;
    int cw0 = px0 - r * WW;                        // row-aligned: 224 % 4 == 0
    const uint32_t* xp = x + (size_t)n * CC * HWP + px0;
    uint32_t w0 = 0, w1 = 0, w2 = 0, w3 = 0;
    #pragma unroll
    for (int c = 0; c < 32; ++c) {
        uint4 v = *reinterpret_cast<const uint4*>(xp + (size_t)c * HWP);
        w0 |= (v.x >> 31) << c;
        w1 |= (v.y >> 31) << c;
        w2 |= (v.z >> 31) << c;
        w3 |= (v.w >> 31) << c;
    }
    uint32_t* op = sp + (size_t)n * PSZ + (r + 1) * PW + (cw0 + 1);
    op[0] = w0; op[1] = w1; op[2] = w2; op[3] = w3;
}

// ============ LDS staging: weights [32][12] (16B rows) + border table ============
// Ctab[ty][oc] = sum over pad taps of (32 - 2*popc(w)); ty bits: 1=top,2=bot,4=left,8=right
__device__ __forceinline__ void stage_lds(const uint32_t* __restrict__ wp,
                                          uint32_t (*Wl)[12], int (*Ctab)[32]) {
    for (int i = threadIdx.x; i < 288; i += 256) {
        int oc = i / 9, k = i - oc * 9;
        Wl[oc][k] = wp[i];
    }
    for (int i = threadIdx.x; i < 512; i += 256) {
        int ty = i >> 5, oc = i & 31;
        int s = 0;
        #pragma unroll
        for (int t = 0; t < 9; ++t) {
            int dh = t / 3 - 1, dw = t % 3 - 1;
            bool pad = ((ty & 1) && dh < 0) || ((ty & 2) && dh > 0) ||
                       ((ty & 4) && dw < 0) || ((ty & 8) && dw > 0);
            if (pad) s += 32 - 2 * __popc(wp[oc * 9 + t]);
        }
        Ctab[ty][oc] = s;
    }
}

// ============ common: thread -> (n, row, col-group) ============
__device__ __forceinline__ void decode_grp(int t, int& n, int& r, int& cw0) {
    n = t / 12544;                 // 56 groups * 224 rows per image
    int rem = t - n * 12544;
    r = rem / 56;
    cw0 = (rem - r * 56) * 4;
}

// 18 tap words for 4 consecutive pixels (row-aligned), padded layout
#define LOAD_TAPS18(base)                                                        \
    uint32_t u0 = (base)[-PW-1], u1 = (base)[-PW],   u2 = (base)[-PW+1],         \
             u3 = (base)[-PW+2], u4 = (base)[-PW+3], u5 = (base)[-PW+4];         \
    uint32_t m0 = (base)[-1],    m1 = (base)[0],     m2 = (base)[1],             \
             m3 = (base)[2],     m4 = (base)[3],     m5 = (base)[4];             \
    uint32_t l0 = (base)[PW-1],  l1 = (base)[PW],    l2 = (base)[PW+1],          \
             l3 = (base)[PW+2],  l4 = (base)[PW+3],  l5 = (base)[PW+4];

// Per-oc conv of 4 px, weights + border corr from LDS.
// sched_barrier(0) pins the LDS reads to their iteration -> no 288-load hoist/spill.
#define CONV4L(oc_)                                                              \
    __builtin_amdgcn_sched_barrier(0);                                           \
    const uint32_t* wr = &Wl[oc_][0];                                            \
    uint32_t w0 = wr[0], w1 = wr[1], w2 = wr[2], w3 = wr[3], w4 = wr[4],         \
             w5 = wr[5], w6 = wr[6], w7 = wr[7], w8 = wr[8];                     \
    int pc0 = __popc(u0^w0)+__popc(u1^w1)+__popc(u2^w2)                          \
            + __popc(m0^w3)+__popc(m1^w4)+__popc(m2^w5)                          \
            + __popc(l0^w6)+__popc(l1^w7)+__popc(l2^w8);                         \
    int pc1 = __popc(u1^w0)+__popc(u2^w1)+__popc(u3^w2)                          \
            + __popc(m1^w3)+__popc(m2^w4)+__popc(m3^w5)                          \
            + __popc(l1^w6)+__popc(l2^w7)+__popc(l3^w8);                         \
    int pc2 = __popc(u2^w0)+__popc(u3^w1)+__popc(u4^w2)                          \
            + __popc(m2^w3)+__popc(m3^w4)+__popc(m4^w5)                          \
            + __popc(l2^w6)+__popc(l3^w7)+__popc(l4^w8);                         \
    int pc3 = __popc(u3^w0)+__popc(u4^w1)+__popc(u5^w2)                          \
            + __popc(m3^w3)+__popc(m4^w4)+__popc(m5^w5)                          \
            + __popc(l3^w6)+__popc(l4^w7)+__popc(l5^w8);                         \
    int c0 = 288 - 2*pc0 - Ctab[ty0][oc_];                                       \
    int c1 = 288 - 2*pc1 - Ctab[rb][oc_];                                        \
    int c2 = 288 - 2*pc2 - Ctab[rb][oc_];                                        \
    int c3 = 288 - 2*pc3 - Ctab[ty3][oc_];

#define DECODE_BORDER()                                                          \
    int rb = (r == 0) ? 1 : (r == HH - 1) ? 2 : 0;                               \
    int ty0 = rb | ((cw0 == 0) ? 4 : 0);                                         \
    int ty3 = rb | ((cw0 == WW - 4) ? 8 : 0);

// ============ conv + exact per-channel sum / sumsq ============
// Per-oc immediate butterfly reduce; only 2 scalar accumulators live across
// the fenced conv iterations (round-3's acc_s[32]/acc_q[32] caused reg churn).
__global__ void __launch_bounds__(256) k_stats(const uint32_t* __restrict__ sp,
                                               const uint32_t* __restrict__ wp,
                                               int* __restrict__ g_sum,
                                               unsigned long long* __restrict__ g_sq) {
    __shared__ __align__(16) uint32_t Wl[32][12];
    __shared__ int Ctab[16][32];
    stage_lds(wp, Wl, Ctab);
    __syncthreads();

    int t = blockIdx.x * 256 + threadIdx.x;        // 784 blocks, 4 px/thread
    int n, r, cw0; decode_grp(t, n, r, cw0);
    const uint32_t* base = sp + (size_t)n * PSZ + (r + 1) * PW + (cw0 + 1);
    LOAD_TAPS18(base)
    DECODE_BORDER()

    int lane = threadIdx.x & 63;
    int lane31 = lane & 31;
    int myS = 0, myQ = 0;
    #pragma unroll
    for (int oc = 0; oc < 32; ++oc) {
        CONV4L(oc)
        int s = c0 + c1 + c2 + c3;
        int q = c0*c0 + c1*c1 + c2*c2 + c3*c3;
        // 5-step butterfly -> each lane holds its 32-lane-half sum
        #pragma unroll
        for (int d = 1; d <= 16; d <<= 1) {
            s += __shfl_xor(s, d, 64);
            q += __shfl_xor(q, d, 64);
        }
        if (lane31 == oc) { myS = s; myQ = q; }    // lane L owns channel L (both halves)
    }
    // merge the two 32-lane halves
    myS += __shfl_xor(myS, 32, 64);
    myQ += __shfl_xor(myQ, 32, 64);

    __shared__ int ls[4][32], lq[4][32];
    int wid = threadIdx.x >> 6;
    if (lane < 32) { ls[wid][lane] = myS; lq[wid][lane] = myQ; }
    __syncthreads();
    if (threadIdx.x < 32) {
        int s = ls[0][threadIdx.x] + ls[1][threadIdx.x] + ls[2][threadIdx.x] + ls[3][threadIdx.x];
        int q = lq[0][threadIdx.x] + lq[1][threadIdx.x] + lq[2][threadIdx.x] + lq[3][threadIdx.x];
        atomicAdd(&g_sum[threadIdx.x], s);
        atomicAdd(&g_sq[threadIdx.x], (unsigned long long)(long long)q);
    }
}

// ============ per-block BN affine from exact int stats ============
__device__ __forceinline__ void build_affine(const int* __restrict__ g_sum,
                                             const unsigned long long* __restrict__ g_sq,
                                             const float* __restrict__ gamma,
                                             const float* __restrict__ beta,
                                             float* aL, float* dL) {
    if (threadIdx.x < 32) {
        int c = threadIdx.x;
        double M = (double)NHWP;
        double mean = (double)g_sum[c] / M;
        double ex2 = (double)(long long)g_sq[c] / M;
        double var = ex2 - mean * mean;
        double inv = 1.0 / sqrt(var + 1e-5);
        double aa = inv * (double)gamma[c];
        aL[c] = (float)aa;
        dL[c] = (float)((double)beta[c] - aa * mean);
    }
}

// ============ conv1 + BN1 + sign -> packed padded s2 ============
__global__ void __launch_bounds__(256) k_sign(const uint32_t* __restrict__ sp,
                                              const uint32_t* __restrict__ wp,
                                              const int* __restrict__ g_sum,
                                              const unsigned long long* __restrict__ g_sq,
                                              const float* __restrict__ gamma,
                                              const float* __restrict__ beta,
                                              uint32_t* __restrict__ op) {
    __shared__ __align__(16) uint32_t Wl[32][12];
    __shared__ int Ctab[16][32];
    __shared__ float aL[32], dL[32];
    stage_lds(wp, Wl, Ctab);
    build_affine(g_sum, g_sq, gamma, beta, aL, dL);
    __syncthreads();

    int t = blockIdx.x * 256 + threadIdx.x;        // 784 blocks, 4 px/thread
    int n, r, cw0; decode_grp(t, n, r, cw0);
    const uint32_t* base = sp + (size_t)n * PSZ + (r + 1) * PW + (cw0 + 1);
    LOAD_TAPS18(base)
    DECODE_BORDER()

    uint32_t wd0 = 0, wd1 = 0, wd2 = 0, wd3 = 0;
    #pragma unroll
    for (int oc = 0; oc < 32; ++oc) {
        CONV4L(oc)
        float a = aL[oc], d = dL[oc];
        // fma never produces -0 unless result is exactly 0 -> sign bit == (y < 0)
        wd0 |= (__float_as_uint(fmaf(a, (float)c0, d)) >> 31) << oc;
        wd1 |= (__float_as_uint(fmaf(a, (float)c1, d)) >> 31) << oc;
        wd2 |= (__float_as_uint(fmaf(a, (float)c2, d)) >> 31) << oc;
        wd3 |= (__float_as_uint(fmaf(a, (float)c3, d)) >> 31) << oc;
    }
    uint32_t* o = op + (size_t)n * PSZ + (r + 1) * PW + (cw0 + 1);
    o[0] = wd0; o[1] = wd1; o[2] = wd2; o[3] = wd3;
}

// ============ conv2 + BN2 + residual -> f32 out (float4 IO) ============
__global__ void __launch_bounds__(256) k_res(const uint32_t* __restrict__ sp,
                                             const uint32_t* __restrict__ wp,
                                             const int* __restrict__ g_sum,
                                             const unsigned long long* __restrict__ g_sq,
                                             const float* __restrict__ gamma,
                                             const float* __restrict__ beta,
                                             const float* __restrict__ x,
                                             float* __restrict__ out) {
    __shared__ __align__(16) uint32_t Wl[32][12];
    __shared__ int Ctab[16][32];
    __shared__ float aL[32], dL[32];
    stage_lds(wp, Wl, Ctab);
    build_affine(g_sum, g_sq, gamma, beta, aL, dL);
    __syncthreads();

    int t = blockIdx.x * 256 + threadIdx.x;        // 784 blocks, 4 px/thread
    int n, r, cw0; decode_grp(t, n, r, cw0);
    const uint32_t* base = sp + (size_t)n * PSZ + (r + 1) * PW + (cw0 + 1);
    LOAD_TAPS18(base)
    DECODE_BORDER()

    size_t pix = (size_t)n * CC * HWP + (size_t)r * WW + cw0;   // 16B aligned
    #pragma unroll
    for (int oc = 0; oc < 32; ++oc) {
        CONV4L(oc)
        float a = aL[oc], d = dL[oc];
        float4 xv = *reinterpret_cast<const float4*>(x + pix + (size_t)oc * HWP);
        float4 ov;
        ov.x = xv.x + fmaf(a, (float)c0, d);
        ov.y = xv.y + fmaf(a, (float)c1, d);
        ov.z = xv.z + fmaf(a, (float)c2, d);
        ov.w = xv.w + fmaf(a, (float)c3, d);
        *reinterpret_cast<float4*>(out + pix + (size_t)oc * HWP) = ov;
    }
}

extern "C" void kernel_launch(void* const* d_in, const int* in_sizes, int n_in,
                              void* d_out, int out_size, void* d_ws, size_t ws_size,
                              hipStream_t stream) {
    const float* x  = (const float*)d_in[0];
    const float* w1 = (const float*)d_in[1];
    const float* g1 = (const float*)d_in[2];
    const float* b1 = (const float*)d_in[3];
    const float* w2 = (const float*)d_in[4];
    const float* g2 = (const float*)d_in[5];
    const float* b2 = (const float*)d_in[6];
    float* out = (float*)d_out;

    char* ws = (char*)d_ws;
    uint32_t* s1  = (uint32_t*)(ws + OFF_S1);
    uint32_t* s2  = (uint32_t*)(ws + OFF_S2);
    uint32_t* wp1 = (uint32_t*)(ws + OFF_WP1);
    uint32_t* wp2 = (uint32_t*)(ws + OFF_WP2);
    unsigned long long* sq1 = (unsigned long long*)(ws + OFF_SQ1);
    unsigned long long* sq2 = (unsigned long long*)(ws + OFF_SQ2);
    int* sum1 = (int*)(ws + OFF_SUM1);
    int* sum2 = (int*)(ws + OFF_SUM2);

    k_setup<<<120, 256, 0, stream>>>((const uint32_t*)w1, (const uint32_t*)w2, ws);
    k_packx<<<784, 256, 0, stream>>>((const uint32_t*)x, s1);
    k_stats<<<784, 256, 0, stream>>>(s1, wp1, sum1, sq1);
    k_sign <<<784, 256, 0, stream>>>(s1, wp1, sum1, sq1, g1, b1, s2);
    k_stats<<<784, 256, 0, stream>>>(s2, wp2, sum2, sq2);
    k_res  <<<784, 256, 0, stream>>>(s2, wp2, sum2, sq2, g2, b2, x, out);
}